// Round 12
// baseline (423.372 us; speedup 1.0000x reference)
//
#include <hip/hip_runtime.h>
#include <math.h>

#define B 128
#define N 1000
#define D 512
#define H 8
#define NCH 10       // chunks for kb/kc (100 rows each)
#define CHK 100
#define NCHM 25      // chunks for k1 (40 rows each; divisible by 4)
#define CHKM 40

// workspace layout. emb16 (bf16 copy of emb, packed u32 pairs) at front.
#define EMB16_FLOATS (B*N*D/2)
#define OFF_QW    EMB16_FLOATS                       // [B][H][D]
#define OFF_PMEAN (OFF_QW + B*H*D)                   // [B][NCHM][D]
#define OFF_PAE   (OFF_PMEAN + B*NCHM*D)             // [B][NCH][H][D]
#define OFF_ZC    (OFF_PAE + B*NCH*H*D)              // [B][NCH][H]
#define OFF_GW    (OFF_ZC + B*NCH*H)                 // [B][D]
#define OFF_LG    (OFF_GW + B*D)                     // [B][N]
#define OFF_LMAX  (OFF_LG + B*N)                     // [B][NCH]
#define OFF_LSUM  (OFF_LMAX + B*NCH)                 // [B][NCH]
#define OFF_PROBE (OFF_LSUM + B*NCH)                 // probe scratch (~41k floats)

__device__ inline unsigned int f2bf(float f){   // bf16 RNE, as low 16 bits
    unsigned int u = __float_as_uint(f);
    return (u + 0x7FFFu + ((u >> 16) & 1u)) >> 16;
}
__device__ inline unsigned int packbf(float lo, float hi){
    return f2bf(lo) | (f2bf(hi) << 16);
}
__device__ inline float bflo(unsigned int u){ return __uint_as_float(u << 16); }
__device__ inline float bfhi(unsigned int u){ return __uint_as_float(u & 0xffff0000u); }

// K1: the ONLY d_in[0] reader: batch-4 loads, partial means + packed bf16 copy.
// grid(NCHM, B), block 128. thread t owns float4 column t.
__global__ __launch_bounds__(128) void k1_convert_mean(const float* __restrict__ emb,
        float* __restrict__ ws){
    int chunk = blockIdx.x, b = blockIdx.y, t = threadIdx.x;
    const size_t row0 = (size_t)b * N + (size_t)chunk * CHKM;
    const float4* e4 = (const float4*)emb + row0 * (D / 4) + t;
    uint2* o2 = (uint2*)ws;    // 1 uint2 = 4 bf16 = one float4 column
    float4 a0 = make_float4(0,0,0,0), a1 = a0, a2 = a0, a3 = a0;
    for (int n = 0; n < CHKM; n += 4) {
        float4 v0 = e4[(size_t)(n + 0) * (D / 4)];
        float4 v1 = e4[(size_t)(n + 1) * (D / 4)];
        float4 v2 = e4[(size_t)(n + 2) * (D / 4)];
        float4 v3 = e4[(size_t)(n + 3) * (D / 4)];
        a0.x += v0.x; a0.y += v0.y; a0.z += v0.z; a0.w += v0.w;
        a1.x += v1.x; a1.y += v1.y; a1.z += v1.z; a1.w += v1.w;
        a2.x += v2.x; a2.y += v2.y; a2.z += v2.z; a2.w += v2.w;
        a3.x += v3.x; a3.y += v3.y; a3.z += v3.z; a3.w += v3.w;
        size_t w0 = (row0 + n) * (D / 4) + t;
        o2[w0]                 = make_uint2(packbf(v0.x, v0.y), packbf(v0.z, v0.w));
        o2[w0 + (D / 4)]       = make_uint2(packbf(v1.x, v1.y), packbf(v1.z, v1.w));
        o2[w0 + 2 * (D / 4)]   = make_uint2(packbf(v2.x, v2.y), packbf(v2.z, v2.w));
        o2[w0 + 3 * (D / 4)]   = make_uint2(packbf(v3.x, v3.y), packbf(v3.z, v3.w));
    }
    float4 acc;
    acc.x = (a0.x + a1.x) + (a2.x + a3.x);
    acc.y = (a0.y + a1.y) + (a2.y + a3.y);
    acc.z = (a0.z + a1.z) + (a2.z + a3.z);
    acc.w = (a0.w + a1.w) + (a2.w + a3.w);
    ((float4*)(ws + OFF_PMEAN + (size_t)(b * NCHM + chunk) * D))[t] = acc;
}

// K2: graph_embed -> query -> qW[b][h][d]. grid(B), block 512
__global__ void k2_prep(const float* __restrict__ stepc, const float* __restrict__ Wnode,
                        const float* __restrict__ Wfix, const float* __restrict__ Wstep,
                        float* __restrict__ ws){
    int b = blockIdx.x, d = threadIdx.x;
    __shared__ float ge[D];
    __shared__ float q[D];
    float s = 0.f;
    #pragma unroll
    for (int c = 0; c < NCHM; ++c) s += ws[OFF_PMEAN + (size_t)(b * NCHM + c) * D + d];
    ge[d] = s * (1.0f / N);
    __syncthreads();
    float a0 = 0.f, a1 = 0.f, a2 = 0.f, a3 = 0.f;
    for (int k = 0; k < D; k += 4) {
        a0 = fmaf(ge[k],     Wfix[(size_t)k * D + d],       a0);
        a1 = fmaf(ge[k + 1], Wfix[(size_t)(k + 1) * D + d], a1);
        a2 = fmaf(ge[k + 2], Wfix[(size_t)(k + 2) * D + d], a2);
        a3 = fmaf(ge[k + 3], Wfix[(size_t)(k + 3) * D + d], a3);
    }
    const float* sc = stepc + (size_t)b * 2 * D;
    for (int k = 0; k < 2 * D; k += 4) {
        a0 = fmaf(sc[k],     Wstep[(size_t)k * D + d],       a0);
        a1 = fmaf(sc[k + 1], Wstep[(size_t)(k + 1) * D + d], a1);
        a2 = fmaf(sc[k + 2], Wstep[(size_t)(k + 2) * D + d], a2);
        a3 = fmaf(sc[k + 3], Wstep[(size_t)(k + 3) * D + d], a3);
    }
    q[d] = (a0 + a1) + (a2 + a3);
    __syncthreads();
    const float* wrow = Wnode + (size_t)d * 3 * D + D;  // gv slice of row d
    #pragma unroll
    for (int h = 0; h < H; ++h) {
        float a = 0.f;
        const float* qh = q + h * 64;
        const float* wh = wrow + h * 64;
        #pragma unroll 8
        for (int s2 = 0; s2 < 64; ++s2) a = fmaf(qh[s2], wh[s2], a);
        ws[OFF_QW + ((size_t)b * H + h) * D + d] = a;   // [b][h][d]
    }
}

// KB: scores + exp + z + PV from bf16 copy. grid(NCH, B), block 256 = 4 waves.
// Phase B: wave-per-row lane d-split, BATCH-5 row loads (5x16B in flight/lane),
// 16-lane-group reduce + LDS combine. Phase E: PV with BATCH-8 loads.
__global__ __launch_bounds__(256) void kb_attn(const unsigned char* __restrict__ mask,
        float* __restrict__ ws){
    const int cg = blockIdx.x, b = blockIdx.y, t = threadIdx.x;
    const int w = t >> 6, l = t & 63, g = l >> 4;
    __shared__ float part[CHK][4][H];   // 12.8 KB
    __shared__ float p_lds[CHK][H];     // 3.2 KB
    __shared__ float zsh[H];
    if (t < H) zsh[t] = 0.f;
    const float* qp = ws + OFF_QW + (size_t)b * H * D + 8 * l;
#define QD(h) float4 qa##h = *(const float4*)(qp + (h) * D); \
              float4 qc##h = *(const float4*)(qp + (h) * D + 4);
    QD(0) QD(1) QD(2) QD(3) QD(4) QD(5) QD(6) QD(7)
#undef QD
    const unsigned int* e16 = (const unsigned int*)ws;
    const size_t rowu = D / 2;
    const size_t base = ((size_t)b * N + (size_t)cg * CHK) * rowu;
    // phase B: 25 rows per wave = 5 batches of 5
    for (int j = 0; j < 5; ++j) {
        uint4 u[5];
        #pragma unroll
        for (int k = 0; k < 5; ++k) {
            int nl = 4 * (5 * j + k) + w;
            u[k] = *(const uint4*)(e16 + base + (size_t)nl * rowu + 4 * l);
        }
        #pragma unroll
        for (int k = 0; k < 5; ++k) {
            int nl = 4 * (5 * j + k) + w;
            float e0 = bflo(u[k].x), e1 = bfhi(u[k].x), e2 = bflo(u[k].y), e3 = bfhi(u[k].y);
            float e4v = bflo(u[k].z), e5 = bfhi(u[k].z), e6 = bflo(u[k].w), e7 = bfhi(u[k].w);
            float s0, s1, s2, s3, s4, s5, s6, s7;
#define DOT(h, dst) { \
            float r = e0 * qa##h.x; r = fmaf(e1, qa##h.y, r); r = fmaf(e2, qa##h.z, r); \
            r = fmaf(e3, qa##h.w, r); r = fmaf(e4v, qc##h.x, r); r = fmaf(e5, qc##h.y, r); \
            r = fmaf(e6, qc##h.z, r); r = fmaf(e7, qc##h.w, r); dst = r; }
            DOT(0, s0) DOT(1, s1) DOT(2, s2) DOT(3, s3)
            DOT(4, s4) DOT(5, s5) DOT(6, s6) DOT(7, s7)
#undef DOT
            #pragma unroll
            for (int o = 1; o <= 8; o <<= 1) {
                s0 += __shfl_xor(s0, o); s1 += __shfl_xor(s1, o);
                s2 += __shfl_xor(s2, o); s3 += __shfl_xor(s3, o);
                s4 += __shfl_xor(s4, o); s5 += __shfl_xor(s5, o);
                s6 += __shfl_xor(s6, o); s7 += __shfl_xor(s7, o);
            }
            if ((l & 15) == 0) {
                *(float4*)&part[nl][g][0] = make_float4(s0, s1, s2, s3);
                *(float4*)&part[nl][g][4] = make_float4(s4, s5, s6, s7);
            }
        }
    }
    __syncthreads();
    const unsigned char* mb = mask + (size_t)b * N + cg * CHK;
    for (int slot = t; slot < CHK * H; slot += 256) {
        int r = slot >> 3, h = slot & 7;
        float v = (part[r][0][h] + part[r][1][h]) + (part[r][2][h] + part[r][3][h]);
        bool m = mb[r] != 0;
        float pe = m ? __expf(v * 0.125f) : 0.f;
        p_lds[r][h] = pe;
        atomicAdd(&zsh[h], pe);
    }
    __syncthreads();
    if (t < H) ws[OFF_ZC + ((size_t)b * NCH + cg) * H + t] = zsh[t];
    // phase E: PV, thread t owns u32 column (2 cols), batch-8 row loads
    {
        float2 acc[H];
        #pragma unroll
        for (int h = 0; h < H; ++h) acc[h] = make_float2(0.f, 0.f);
        const unsigned int* ecol = e16 + base + t;
#define PVROW(idx, uv) { \
        float ex = bflo(uv), ey = bfhi(uv); \
        float4 pa = *(const float4*)&p_lds[idx][0]; \
        float4 pb = *(const float4*)&p_lds[idx][4]; \
        acc[0].x = fmaf(pa.x, ex, acc[0].x); acc[0].y = fmaf(pa.x, ey, acc[0].y); \
        acc[1].x = fmaf(pa.y, ex, acc[1].x); acc[1].y = fmaf(pa.y, ey, acc[1].y); \
        acc[2].x = fmaf(pa.z, ex, acc[2].x); acc[2].y = fmaf(pa.z, ey, acc[2].y); \
        acc[3].x = fmaf(pa.w, ex, acc[3].x); acc[3].y = fmaf(pa.w, ey, acc[3].y); \
        acc[4].x = fmaf(pb.x, ex, acc[4].x); acc[4].y = fmaf(pb.x, ey, acc[4].y); \
        acc[5].x = fmaf(pb.y, ex, acc[5].x); acc[5].y = fmaf(pb.y, ey, acc[5].y); \
        acc[6].x = fmaf(pb.z, ex, acc[6].x); acc[6].y = fmaf(pb.z, ey, acc[6].y); \
        acc[7].x = fmaf(pb.w, ex, acc[7].x); acc[7].y = fmaf(pb.w, ey, acc[7].y); }
        for (int i0 = 0; i0 < 96; i0 += 8) {
            unsigned int u[8];
            #pragma unroll
            for (int k = 0; k < 8; ++k) u[k] = ecol[(size_t)(i0 + k) * rowu];
            #pragma unroll
            for (int k = 0; k < 8; ++k) PVROW(i0 + k, u[k])
        }
        {
            unsigned int u[4];
            #pragma unroll
            for (int k = 0; k < 4; ++k) u[k] = ecol[(size_t)(96 + k) * rowu];
            #pragma unroll
            for (int k = 0; k < 4; ++k) PVROW(96 + k, u[k])
        }
#undef PVROW
        float2* paeb = (float2*)(ws + OFF_PAE) + ((size_t)(b * NCH + cg) * H) * (D / 2) + t;
        #pragma unroll
        for (int h = 0; h < H; ++h) paeb[(size_t)h * (D / 2)] = acc[h];
    }
}

// KD: combine PV partials -> heads -> glimpse -> gW. grid(B), block 512
__global__ __launch_bounds__(512) void kd_post(const float* __restrict__ Wnode,
        const float* __restrict__ Wout, float* __restrict__ ws){
    int b = blockIdx.x, t = threadIdx.x;
    __shared__ float ae[H * D];
    __shared__ float heads[D];
    __shared__ float gl[D];
    __shared__ float iZ[H];
    if (t < H) {
        float Z = 0.f;
        #pragma unroll
        for (int c = 0; c < NCH; ++c)
            Z += ws[OFF_ZC + ((size_t)b * NCH + c) * H + t];
        iZ[t] = 1.0f / Z;
    }
    __syncthreads();
    #pragma unroll
    for (int h = 0; h < H; ++h) {
        float s = 0.f;
        #pragma unroll
        for (int c = 0; c < NCH; ++c)
            s += ws[OFF_PAE + (((size_t)b * NCH + c) * H + h) * (size_t)D + t];
        ae[h * D + t] = s * iZ[h];
    }
    __syncthreads();
    {
        int h = t >> 6;
        const float* aeh = ae + h * D;
        const float* col = Wnode + 512 + t;
        float a0 = 0.f, a1 = 0.f, a2 = 0.f, a3 = 0.f;
        for (int d = 0; d < D; d += 4) {
            a0 = fmaf(aeh[d],     col[(size_t)d * (3 * D)],       a0);
            a1 = fmaf(aeh[d + 1], col[(size_t)(d + 1) * (3 * D)], a1);
            a2 = fmaf(aeh[d + 2], col[(size_t)(d + 2) * (3 * D)], a2);
            a3 = fmaf(aeh[d + 3], col[(size_t)(d + 3) * (3 * D)], a3);
        }
        heads[t] = (a0 + a1) + (a2 + a3);
    }
    __syncthreads();
    {
        float a0 = 0.f, a1 = 0.f, a2 = 0.f, a3 = 0.f;
        for (int d = 0; d < D; d += 4) {
            a0 = fmaf(heads[d],     Wout[(size_t)d * D + t],       a0);
            a1 = fmaf(heads[d + 1], Wout[(size_t)(d + 1) * D + t], a1);
            a2 = fmaf(heads[d + 2], Wout[(size_t)(d + 2) * D + t], a2);
            a3 = fmaf(heads[d + 3], Wout[(size_t)(d + 3) * D + t], a3);
        }
        gl[t] = (a0 + a1) + (a2 + a3);
    }
    __syncthreads();
    {
        const float* wrow = Wnode + (size_t)t * (3 * D) + 2 * D;
        float a0 = 0.f, a1 = 0.f, a2 = 0.f, a3 = 0.f;
        for (int e = 0; e < D; e += 4) {
            a0 = fmaf(gl[e],     wrow[e],     a0);
            a1 = fmaf(gl[e + 1], wrow[e + 1], a1);
            a2 = fmaf(gl[e + 2], wrow[e + 2], a2);
            a3 = fmaf(gl[e + 3], wrow[e + 3], a3);
        }
        ws[OFF_GW + (size_t)b * D + t] = (a0 + a1) + (a2 + a3);
    }
}

// KC: logits from bf16 copy, batch-5 loads. grid(NCH, B), block 256 = 4 waves.
__global__ __launch_bounds__(256) void kc_logits(const unsigned char* __restrict__ mask,
        float* __restrict__ ws){
    const int cg = blockIdx.x, b = blockIdx.y, t = threadIdx.x;
    const int w = t >> 6, l = t & 63;
    __shared__ float wm[4], wsum[4];
    float4 ga, gb;
    {
        const float* gp = ws + OFF_GW + (size_t)b * D + 8 * l;
        ga = *(const float4*)gp;
        gb = *(const float4*)(gp + 4);
    }
    const unsigned int* e16 = (const unsigned int*)ws;
    const size_t rowu = D / 2;
    const size_t base = ((size_t)b * N + (size_t)cg * CHK) * rowu;
    const unsigned char* mb = mask + (size_t)b * N + cg * CHK;
    float m = -INFINITY, s = 0.f;
    for (int j = 0; j < 5; ++j) {
        uint4 u[5];
        #pragma unroll
        for (int k = 0; k < 5; ++k) {
            int nl = 4 * (5 * j + k) + w;
            u[k] = *(const uint4*)(e16 + base + (size_t)nl * rowu + 4 * l);
        }
        #pragma unroll
        for (int k = 0; k < 5; ++k) {
            int nl = 4 * (5 * j + k) + w;
            float a = bflo(u[k].x) * ga.x;
            a = fmaf(bfhi(u[k].x), ga.y, a);
            a = fmaf(bflo(u[k].y), ga.z, a);
            a = fmaf(bfhi(u[k].y), ga.w, a);
            a = fmaf(bflo(u[k].z), gb.x, a);
            a = fmaf(bfhi(u[k].z), gb.y, a);
            a = fmaf(bflo(u[k].w), gb.z, a);
            a = fmaf(bfhi(u[k].w), gb.w, a);
            #pragma unroll
            for (int o = 32; o > 0; o >>= 1) a += __shfl_xor(a, o);
            bool mk = mb[nl] != 0;
            float lg = mk ? tanhf(a * 0.044194173824159216f) * 10.0f : -INFINITY;
            if (l == 0) ws[OFF_LG + (size_t)b * N + cg * CHK + nl] = lg;
            if (mk) {
                float mn = fmaxf(m, lg);
                s = s * __expf(m - mn) + __expf(lg - mn);
                m = mn;
            }
        }
    }
    if (l == 0) { wm[w] = m; wsum[w] = s; }
    __syncthreads();
    if (t == 0) {
        float M = -INFINITY;
        #pragma unroll
        for (int i = 0; i < 4; ++i) M = fmaxf(M, wm[i]);
        float S = 0.f;
        #pragma unroll
        for (int i = 0; i < 4; ++i)
            if (wm[i] != -INFINITY) S += wsum[i] * __expf(wm[i] - M);
        ws[OFF_LMAX + (size_t)b * NCH + cg] = M;
        ws[OFF_LSUM + (size_t)b * NCH + cg] = S;
    }
}

// K8: combine chunk stats -> L, write output (finite sentinel at masked).
__global__ void k8_out(const float* __restrict__ ws, float* __restrict__ out){
    int b = blockIdx.x, t = threadIdx.x;
    __shared__ float Ls;
    if (t == 0) {
        float M = -INFINITY;
        #pragma unroll
        for (int c = 0; c < NCH; ++c)
            M = fmaxf(M, ws[OFF_LMAX + (size_t)b * NCH + c]);
        float S = 0.f;
        #pragma unroll
        for (int c = 0; c < NCH; ++c) {
            float m = ws[OFF_LMAX + (size_t)b * NCH + c];
            if (m != -INFINITY) S += __expf(m - M) * ws[OFF_LSUM + (size_t)b * NCH + c];
        }
        Ls = M + __logf(S);
    }
    __syncthreads();
    float L = Ls;
    for (int j = t; j < N; j += 256)
        out[(size_t)b * N + j] = fmaxf(ws[OFF_LG + (size_t)b * N + j] - L, -1e30f);
}

// ---- PROBES (diagnostic; write only to OFF_PROBE region) ----

// P1: streaming read of ws bf16 region, batch-8 uint4. grid 4000 x 256.
// 8,192,000 uint4 = 8 * 4000 * 256 exactly.
__global__ __launch_bounds__(256) void probe_stream_ws(const float* __restrict__ ws,
        float* __restrict__ outp){
    const uint4* p = (const uint4*)ws;
    const size_t tid = (size_t)blockIdx.x * 256 + threadIdx.x;
    const size_t STR = 4000u * 256u;
    unsigned int r = 0;
    uint4 v[8];
    #pragma unroll
    for (int k = 0; k < 8; ++k) v[k] = p[tid + (size_t)k * STR];
    #pragma unroll
    for (int k = 0; k < 8; ++k) r ^= v[k].x ^ v[k].y ^ v[k].z ^ v[k].w;
    #pragma unroll
    for (int o = 32; o > 0; o >>= 1) r ^= (unsigned int)__shfl_xor((int)r, o);
    if ((threadIdx.x & 63) == 0)
        outp[blockIdx.x * 4 + (threadIdx.x >> 6)] = (float)(r & 0xff);
}

// P2: streaming read of d_in[0] fp32, batch-8 float4 x2. grid 4000 x 256.
// 16,384,000 float4 = 16 * 4000 * 256 exactly.
__global__ __launch_bounds__(256) void probe_stream_in(const float* __restrict__ emb,
        float* __restrict__ outp){
    const float4* p = (const float4*)emb;
    const size_t tid = (size_t)blockIdx.x * 256 + threadIdx.x;
    const size_t STR = 4000u * 256u;
    float r = 0.f;
    #pragma unroll
    for (int half = 0; half < 2; ++half) {
        float4 v[8];
        #pragma unroll
        for (int k = 0; k < 8; ++k) v[k] = p[tid + (size_t)(half * 8 + k) * STR];
        #pragma unroll
        for (int k = 0; k < 8; ++k) r += (v[k].x + v[k].y) + (v[k].z + v[k].w);
    }
    #pragma unroll
    for (int o = 32; o > 0; o >>= 1) r += __shfl_xor(r, o);
    if ((threadIdx.x & 63) == 0)
        outp[16000 + blockIdx.x * 4 + (threadIdx.x >> 6)] = r;
}

// P3: kb row pattern, batch-5, no butterfly. grid (NCH, B) x 256.
__global__ __launch_bounds__(256) void probe_rows(const float* __restrict__ ws,
        float* __restrict__ outp){
    const int cg = blockIdx.x, b = blockIdx.y, t = threadIdx.x;
    const int w = t >> 6, l = t & 63;
    const unsigned int* e16 = (const unsigned int*)ws;
    const size_t rowu = D / 2;
    const size_t base = ((size_t)b * N + (size_t)cg * CHK) * rowu;
    unsigned int r = 0;
    for (int j = 0; j < 5; ++j) {
        uint4 u[5];
        #pragma unroll
        for (int k = 0; k < 5; ++k) {
            int nl = 4 * (5 * j + k) + w;
            u[k] = *(const uint4*)(e16 + base + (size_t)nl * rowu + 4 * l);
        }
        #pragma unroll
        for (int k = 0; k < 5; ++k) r ^= u[k].x ^ u[k].y ^ u[k].z ^ u[k].w;
    }
    #pragma unroll
    for (int o = 32; o > 0; o >>= 1) r ^= (unsigned int)__shfl_xor((int)r, o);
    if (l == 0)
        outp[32000 + (b * NCH + cg) * 4 + w] = (float)(r & 0xff);
}

extern "C" void kernel_launch(void* const* d_in, const int* in_sizes, int n_in,
                              void* d_out, int out_size, void* d_ws, size_t ws_size,
                              hipStream_t stream) {
    const float* emb   = (const float*)d_in[0];
    const float* stepc = (const float*)d_in[1];
    const unsigned char* mask = (const unsigned char*)d_in[2];
    const float* Wnode = (const float*)d_in[3];
    const float* Wfix  = (const float*)d_in[4];
    const float* Wstep = (const float*)d_in[5];
    const float* Wout  = (const float*)d_in[6];
    float* out = (float*)d_out;
    float* ws  = (float*)d_ws;

    k1_convert_mean<<<dim3(NCHM, B), 128, 0, stream>>>(emb, ws);
    k2_prep<<<dim3(B), 512, 0, stream>>>(stepc, Wnode, Wfix, Wstep, ws);
    kb_attn<<<dim3(NCH, B), 256, 0, stream>>>(mask, ws);
    kd_post<<<dim3(B), 512, 0, stream>>>(Wnode, Wout, ws);
    kc_logits<<<dim3(NCH, B), 256, 0, stream>>>(mask, ws);
    k8_out<<<dim3(B), 256, 0, stream>>>(ws, out);
    // diagnostics (write only to OFF_PROBE scratch)
    probe_stream_ws<<<dim3(4000), 256, 0, stream>>>(ws, ws + OFF_PROBE);
    probe_stream_in<<<dim3(4000), 256, 0, stream>>>(emb, ws + OFF_PROBE);
    probe_rows<<<dim3(NCH, B), 256, 0, stream>>>(ws, ws + OFF_PROBE);
}